// Round 8
// baseline (867.373 us; speedup 1.0000x reference)
//
#include <hip/hip_runtime.h>
#include <math.h>

#define N_TOK  131072
#define DIM    1024
#define HIDN   256
#define ATTN   128
#define NSEG   64
#define NBLK   (N_TOK / 64)   // 2048 row-blocks, 32 per segment
#define NCLS   2
#define EPSLN  1e-5f

typedef __attribute__((ext_vector_type(8))) short  short8;
typedef __attribute__((ext_vector_type(4))) float  f32x4;

__device__ __forceinline__ unsigned short f2bf(float f) {
    unsigned int u = __float_as_uint(f);
    u += 0x7fffu + ((u >> 16) & 1u);
    return (unsigned short)(u >> 16);
}
__device__ __forceinline__ float bf2f(unsigned short h) {
    return __uint_as_float(((unsigned int)h) << 16);
}
__device__ __forceinline__ float gelu_exact(float x) {
    return 0.5f * x * (1.0f + erff(x * 0.70710678118654752f));
}
// Branchless GELU: erf via Abramowitz-Stegun 7.1.26 (|eps| <= 1.5e-7).
__device__ __forceinline__ float gelu_fast(float x) {
    const float z  = x * 0.70710678118654752f;
    const float az = fabsf(z);
    const float t  = __builtin_amdgcn_rcpf(fmaf(0.3275911f, az, 1.0f));
    float p = fmaf(t, 1.061405429f, -1.453152027f);
    p = fmaf(t, p, 1.421413741f);
    p = fmaf(t, p, -0.284496736f);
    p = fmaf(t, p, 0.254829592f);
    p *= t;
    const float e  = __expf(-z * z);
    float er = fmaf(-p, e, 1.0f);
    er = copysignf(er, z);
    return 0.5f * x * (1.0f + er);
}
__device__ __forceinline__ float tanh_fast(float x) {
    const float e = __expf(-2.0f * fabsf(x));
    const float r = (1.0f - e) * __builtin_amdgcn_rcpf(1.0f + e);
    return copysignf(r, x);
}
__device__ __forceinline__ float sigmoid_fast(float x) {
    return __builtin_amdgcn_rcpf(1.0f + __expf(-x));
}
// 8 x f32 -> short8 bf16 via v_cvt_pk_bf16_f32 (HW RNE; no builtin on gfx950 -> asm)
__device__ __forceinline__ short8 cvtpk8(float4 v0, float4 v1) {
    union { unsigned int u[4]; short8 s; } r;
    asm("v_cvt_pk_bf16_f32 %0, %1, %2" : "=v"(r.u[0]) : "v"(v0.x), "v"(v0.y));
    asm("v_cvt_pk_bf16_f32 %0, %1, %2" : "=v"(r.u[1]) : "v"(v0.z), "v"(v0.w));
    asm("v_cvt_pk_bf16_f32 %0, %1, %2" : "=v"(r.u[2]) : "v"(v1.x), "v"(v1.y));
    asm("v_cvt_pk_bf16_f32 %0, %1, %2" : "=v"(r.u[3]) : "v"(v1.z), "v"(v1.w));
    return r.s;
}

// Weight prep -> MFMA-fragment order (one coalesced dwordx4 per lane per fragment).
// W1f/W2f fragment ((w*NT+t)*4+j)*64+lane: lane(lr,lq) holds W[k=t*32+lq*8+e][n=64w+16j+lr].
// Wvuf PAIRED: j in {0,1} -> Wv col 32w+16j+lr ; j in {2,3} -> Wu col 32w+16(j-2)+lr.
__global__ __launch_bounds__(256) void prep_weights(const float* __restrict__ W1,
                                                    const float* __restrict__ W2,
                                                    const float* __restrict__ Wv,
                                                    const float* __restrict__ Wu,
                                                    unsigned short* __restrict__ W1f,
                                                    unsigned short* __restrict__ W2f,
                                                    unsigned short* __restrict__ Wvuf) {
    const int b = blockIdx.x, tid = threadIdx.x;
    const int lane = tid & 63;
    const int lr = lane & 15, lq = lane >> 4;
    short8 sv;
    if (b < 128) {
        const int idx = b * 256 + tid;
        const int rem = idx >> 6;                 // (w*32+t)*4+j
        const int j = rem & 3, t = (rem >> 2) & 31, w = rem >> 7;
        const int n = 64 * w + 16 * j + lr;
        const int k = t * 32 + lq * 8;
#pragma unroll
        for (int e = 0; e < 8; e++) sv[e] = (short)f2bf(W1[(size_t)(k + e) * HIDN + n]);
        *(short8*)&W1f[(size_t)idx * 8] = sv;
    } else if (b < 160) {
        const int idx = (b - 128) * 256 + tid;
        const int rem = idx >> 6;                 // (w*8+t)*4+j
        const int j = rem & 3, t = (rem >> 2) & 7, w = rem >> 5;
        const int n = 64 * w + 16 * j + lr;
        const int k = t * 32 + lq * 8;
#pragma unroll
        for (int e = 0; e < 8; e++) sv[e] = (short)f2bf(W2[(size_t)(k + e) * HIDN + n]);
        *(short8*)&W2f[(size_t)idx * 8] = sv;
    } else {
        const int idx = (b - 160) * 256 + tid;
        const int rem = idx >> 6;                 // (w*8+t)*4+j
        const int j = rem & 3, t = (rem >> 2) & 7, w = rem >> 5;
        const int col = 32 * w + 16 * (j & 1) + lr;
        const int k = t * 32 + lq * 8;
        const float* src = (j < 2) ? Wv : Wu;
#pragma unroll
        for (int e = 0; e < 8; e++) sv[e] = (short)f2bf(src[(size_t)(k + e) * ATTN + col]);
        *(short8*)&Wvuf[(size_t)idx * 8] = sv;
    }
}

// Mega-fused per 64-row block. Phase 1: x staged fp32 via async global_load_lds
// (linear LDS dest + XOR-swizzled per-lane global source; ds_read applies the same XOR
// -> 2-way banks, T21-correct). Fragments converted in-wave via v_cvt_pk_bf16_f32.
// Phases 2/3: A from resident HT tile, W coalesced from L2, prefetch depth 2, no barriers.
// LDS map (35840 B): [0..33792) HT[64][264] u16; phase-1 As_f32[2][64][32] (16384 B)
//                    aliases it (phase-disjoint). [33792..35840) red[2][4][64] f32
//                    (score pw[4][64]+es[64] alias it).
__global__ __launch_bounds__(256, 3) void fused_mlp_score(
    const float* __restrict__ x,
    const unsigned short* __restrict__ W1f,
    const unsigned short* __restrict__ W2f,
    const unsigned short* __restrict__ Wvuf,
    const float* __restrict__ b1, const float* __restrict__ g1, const float* __restrict__ be1,
    const float* __restrict__ b2, const float* __restrict__ g2, const float* __restrict__ be2,
    const float* __restrict__ bv, const float* __restrict__ bu,
    const float* __restrict__ Ww, const float* __restrict__ bw,
    float* __restrict__ Zp, float* __restrict__ Se) {
    __shared__ __align__(16) char smem[35840];
    auto HT  = (unsigned short (*)[264])smem;       // [64][264]
    auto red = (float (*)[4][64])(smem + 33792);    // [2][4][64]

    const int tid  = threadIdx.x;
    const int wave = tid >> 6, lane = tid & 63;
    const int lr = lane & 15, lq = lane >> 4;
    const size_t row0 = (size_t)blockIdx.x * 64;

    f32x4 acc[4][4];
    auto zero_acc = [&]() {
#pragma unroll
        for (int i = 0; i < 4; i++)
#pragma unroll
            for (int j = 0; j < 4; j++) acc[i][j] = (f32x4)0.0f;
    };

    auto ln_epilogue = [&](const float* bias, const float* gamma, const float* beta) {
        float bjv[4];
#pragma unroll
        for (int j = 0; j < 4; j++) bjv[j] = bias[wave * 64 + 16 * j + lr];
#pragma unroll
        for (int i = 0; i < 4; i++)
#pragma unroll
            for (int j = 0; j < 4; j++)
#pragma unroll
                for (int r = 0; r < 4; r++) acc[i][j][r] += bjv[j];
#pragma unroll
        for (int i = 0; i < 4; i++)
#pragma unroll
            for (int r = 0; r < 4; r++) {
                float s = 0.0f, sq = 0.0f;
#pragma unroll
                for (int j = 0; j < 4; j++) { float v = acc[i][j][r]; s += v; sq += v * v; }
#pragma unroll
                for (int m = 1; m < 16; m <<= 1) { s += __shfl_xor(s, m); sq += __shfl_xor(sq, m); }
                if (lr == 0) {
                    red[0][wave][16 * i + 4 * lq + r] = s;
                    red[1][wave][16 * i + 4 * lq + r] = sq;
                }
            }
        __syncthreads();
        float gj[4], bej[4];
#pragma unroll
        for (int j = 0; j < 4; j++) {
            gj[j]  = gamma[wave * 64 + 16 * j + lr];
            bej[j] = beta[wave * 64 + 16 * j + lr];
        }
#pragma unroll
        for (int i = 0; i < 4; i++)
#pragma unroll
            for (int r = 0; r < 4; r++) {
                const int row = 16 * i + 4 * lq + r;
                const float s  = red[0][0][row] + red[0][1][row] + red[0][2][row] + red[0][3][row];
                const float sq = red[1][0][row] + red[1][1][row] + red[1][2][row] + red[1][3][row];
                const float mu  = s * (1.0f / HIDN);
                const float var = sq * (1.0f / HIDN) - mu * mu;
                const float rs  = rsqrtf(var + EPSLN);
#pragma unroll
                for (int j = 0; j < 4; j++)
                    HT[row][wave * 64 + 16 * j + lr] =
                        f2bf(gelu_fast((acc[i][j][r] - mu) * rs * gj[j] + bej[j]));
            }
        __syncthreads();   // HT complete before the next phase reads it
    };

    // ---------- phase 1: x @ W1 (K=1024), async fp32 staging, 1 barrier/step ----------
    zero_acc();
    {
        const int wv = __builtin_amdgcn_readfirstlane(wave);
        // stage K-tile t into buffer bufsel: 512 x 16B blocks; this wave covers
        // blocks p*256 + wv*64 + lane (p=0,1). LDS dest is LINEAR (base + lane*16);
        // the global source block is XOR-permuted so LDS holds the swizzled layout.
        auto stage_x = [&](int t, int bufsel) {
#pragma unroll
            for (int p = 0; p < 2; ++p) {
                const int b   = p * 256 + wv * 64 + lane;   // 16B-block index 0..511
                const int row = b >> 3, c = b & 7;          // 8 blocks (32 fp32) per row
                const float* src = &x[(row0 + row) * DIM + t * 32 + ((c ^ (row & 7)) << 2)];
                char* dst = smem + bufsel * 8192 + (p * 256 + wv * 64) * 16;
                __builtin_amdgcn_global_load_lds(
                    (const __attribute__((address_space(1))) void*)src,
                    (__attribute__((address_space(3))) void*)dst, 16, 0, 0);
            }
        };
        const short8* wb = (const short8*)W1f + (size_t)wave * (32 * 4 * 64) + lane;
        short8 bq[2][4];
#pragma unroll
        for (int j = 0; j < 4; ++j) bq[0][j] = wb[j * 64];
        stage_x(0, 0);
        __syncthreads();   // vmcnt drained by compiler -> tile 0 resident
#pragma unroll
        for (int t = 0; t < 32; ++t) {
            if (t + 1 < 32) {
                stage_x(t + 1, (t + 1) & 1);
                const short8* wp = wb + (size_t)(t + 1) * 256;
#pragma unroll
                for (int j = 0; j < 4; ++j) bq[(t + 1) & 1][j] = wp[j * 64];
            }
            short8 a[4];
#pragma unroll
            for (int i = 0; i < 4; ++i) {
                const int row = 16 * i + lr;
                const char* base = smem + (t & 1) * 8192 + row * 128;
                float4 f0 = *(const float4*)(base + ((( 2 * lq )    ^ (row & 7)) << 4));
                float4 f1 = *(const float4*)(base + (((2 * lq + 1) ^ (row & 7)) << 4));
                a[i] = cvtpk8(f0, f1);
            }
#pragma unroll
            for (int i = 0; i < 4; ++i)
#pragma unroll
                for (int j = 0; j < 4; ++j)
                    acc[i][j] = __builtin_amdgcn_mfma_f32_16x16x32_bf16(a[i], bq[t & 1][j], acc[i][j], 0, 0, 0);
            __syncthreads();   // reads of buf[t&1] done + tile t+1 loads landed
        }
    }

    const short8* w2b = (const short8*)W2f  + (size_t)wave * (8 * 4 * 64) + lane;
    const short8* wvb = (const short8*)Wvuf + (size_t)wave * (8 * 4 * 64) + lane;

    // pre-issue phase-2 step-0 W fragments: L2 latency hides under epilogue VALU
    short8 pre[4];
#pragma unroll
    for (int j = 0; j < 4; ++j) pre[j] = w2b[j * 64];

    ln_epilogue(b1, g1, be1);

    // ---------- phases 2/3: HT @ W (K=256), barrier-free, W prefetch depth 2 ----------
    auto gemm_ht = [&](const short8* wb, const short8* pre0) {
        short8 bq[3][4];
#pragma unroll
        for (int j = 0; j < 4; ++j) bq[0][j] = pre0[j];
#pragma unroll
        for (int j = 0; j < 4; ++j) bq[1][j] = wb[256 + j * 64];
#pragma unroll
        for (int t = 0; t < 8; ++t) {
            if (t + 2 < 8) {
                const short8* wp = wb + (size_t)(t + 2) * 256;
#pragma unroll
                for (int j = 0; j < 4; ++j) bq[(t + 2) % 3][j] = wp[j * 64];
            }
            short8 a[4];
#pragma unroll
            for (int i = 0; i < 4; ++i)
                a[i] = *(const short8*)&HT[16 * i + lr][t * 32 + lq * 8];
#pragma unroll
            for (int i = 0; i < 4; ++i)
#pragma unroll
                for (int j = 0; j < 4; ++j)
                    acc[i][j] = __builtin_amdgcn_mfma_f32_16x16x32_bf16(a[i], bq[t % 3][j], acc[i][j], 0, 0, 0);
        }
    };

    zero_acc();
    gemm_ht(w2b, pre);

    // pre-issue phase-3 step-0 W fragments before the second epilogue
#pragma unroll
    for (int j = 0; j < 4; ++j) pre[j] = wvb[j * 64];

    ln_epilogue(b2, g2, be2);   // h2 now resident in HT

    zero_acc();
    gemm_ht(wvb, pre);

    // ---------- score (lane-local v/u pairing) + softmax-pool epilogue ----------
    {
        float bvv[2], buu[2], wwj[2];
#pragma unroll
        for (int j = 0; j < 2; ++j) {
            bvv[j] = bv[32 * wave + 16 * j + lr];
            buu[j] = bu[32 * wave + 16 * j + lr];
            wwj[j] = Ww[32 * wave + 16 * j + lr];
        }
        float (*pw)[64] = (float (*)[64])(smem + 33792);   // [4][64]
        float* es = (float*)(smem + 33792 + 1024);         // [64]
#pragma unroll
        for (int i = 0; i < 4; ++i)
#pragma unroll
            for (int r = 0; r < 4; ++r) {
                const int row = 16 * i + 4 * lq + r;
                float s = 0.0f;
#pragma unroll
                for (int j = 0; j < 2; ++j) {
                    const float vv = acc[i][j][r] + bvv[j];
                    const float uu = acc[i][j + 2][r] + buu[j];
                    s += tanh_fast(vv) * sigmoid_fast(uu) * wwj[j];
                }
#pragma unroll
                for (int m = 1; m < 16; m <<= 1) s += __shfl_xor(s, m);
                if (lr == 0) pw[wave][row] = s;
            }
        __syncthreads();
        if (tid < 64) {
            const float sc = pw[0][tid] + pw[1][tid] + pw[2][tid] + pw[3][tid] + bw[0];
            const float e = __expf(sc);   // |sc| <= sum|Ww| (~9): fp32-safe, shift-invariant
            es[tid] = e;
            float t2 = e;
#pragma unroll
            for (int o = 32; o > 0; o >>= 1) t2 += __shfl_down(t2, o);
            if (tid == 0) Se[blockIdx.x] = t2;
        }
        __syncthreads();
        float pacc = 0.0f;
#pragma unroll 8
        for (int row = 0; row < 64; ++row) pacc += es[row] * bf2f(HT[row][tid]);
        Zp[(size_t)blockIdx.x * 256 + tid] = pacc;
    }
}

// z = (sum of 32 Zp partials) / (sum of 32 Se); logits = gelu(z@Wc1+bc1)@Wc2 + bc2.
__global__ __launch_bounds__(256) void head_kernel(const float* __restrict__ Zp,
                                                   const float* __restrict__ Se,
                                                   const float* __restrict__ Wc1,
                                                   const float* __restrict__ bc1,
                                                   const float* __restrict__ Wc2,
                                                   const float* __restrict__ bc2,
                                                   float* __restrict__ Out) {
    __shared__ float zs[256];
    __shared__ float hs[128];
    __shared__ float red[4];
    const int seg = blockIdx.x, tid = threadIdx.x;
    float z = 0.0f;
#pragma unroll
    for (int c = 0; c < 32; ++c) z += Zp[((size_t)seg * 32 + c) * 256 + tid];
    float den = 0.0f;
#pragma unroll
    for (int c = 0; c < 32; ++c) den += Se[seg * 32 + c];
    zs[tid] = z / den;
    __syncthreads();
    if (tid < 128) {
        float acc = bc1[tid];
        for (int k = 0; k < 256; k++) acc += zs[k] * Wc1[k * 128 + tid];
        hs[tid] = gelu_exact(acc);
    }
    __syncthreads();
    const int cls = tid >> 7, j = tid & 127;
    float val = hs[j] * Wc2[j * 2 + cls];
#pragma unroll
    for (int o = 32; o > 0; o >>= 1) val += __shfl_down(val, o);
    if ((tid & 63) == 0) red[tid >> 6] = val;
    __syncthreads();
    if (tid < 2) Out[seg * 2 + tid] = red[tid * 2] + red[tid * 2 + 1] + bc2[tid];
}

extern "C" void kernel_launch(void* const* d_in, const int* in_sizes, int n_in,
                              void* d_out, int out_size, void* d_ws, size_t ws_size,
                              hipStream_t stream) {
    const float* x   = (const float*)d_in[0];
    const float* W1  = (const float*)d_in[2];
    const float* b1  = (const float*)d_in[3];
    const float* g1  = (const float*)d_in[4];
    const float* be1 = (const float*)d_in[5];
    const float* W2  = (const float*)d_in[6];
    const float* b2  = (const float*)d_in[7];
    const float* g2  = (const float*)d_in[8];
    const float* be2 = (const float*)d_in[9];
    const float* Wv  = (const float*)d_in[10];
    const float* bv  = (const float*)d_in[11];
    const float* Wu  = (const float*)d_in[12];
    const float* bu  = (const float*)d_in[13];
    const float* Ww  = (const float*)d_in[14];
    const float* bw  = (const float*)d_in[15];
    const float* Wc1 = (const float*)d_in[16];
    const float* bc1 = (const float*)d_in[17];
    const float* Wc2 = (const float*)d_in[18];
    const float* bc2 = (const float*)d_in[19];
    float* out = (float*)d_out;

    char* p = (char*)d_ws;
    unsigned short* W1f  = (unsigned short*)p; p += (size_t)HIDN * DIM * 2;
    unsigned short* W2f  = (unsigned short*)p; p += (size_t)HIDN * HIDN * 2;
    unsigned short* Wvuf = (unsigned short*)p; p += (size_t)HIDN * HIDN * 2;
    float*          Zp   = (float*)p;          p += (size_t)NBLK * HIDN * 4;
    float*          Se   = (float*)p;          p += (size_t)NBLK * 4;

    prep_weights<<<192, 256, 0, stream>>>(W1, W2, Wv, Wu, W1f, W2f, Wvuf);

    fused_mlp_score<<<NBLK, 256, 0, stream>>>(
        x, W1f, W2f, Wvuf,
        b1, g1, be1, b2, g2, be2,
        bv, bu, Ww, bw, Zp, Se);

    head_kernel<<<NSEG, 256, 0, stream>>>(Zp, Se, Wc1, bc1, Wc2, bc2, out);
}